// Round 1
// baseline (128.640 us; speedup 1.0000x reference)
//
#include <hip/hip_runtime.h>

// IndexedLinear: out[z, s*V:(s+1)*V] = coeff[s] * x[z, s*U:(s+1)*U] @ W[seg(z), s]
// S=8, U=V=32, C=32 segments, Z=65536.
// Memory-bound (~129 MiB min traffic -> ~20.5us @ 6.3 TB/s). Strategy:
//  - grid = (Z/BZ) * S blocks; block handles one (z-tile, s) pair.
//  - stage X^T [u][z] in LDS (stride 132: mult-of-4 for b128 reads, odd/32 for banks)
//  - stage W (coeff pre-folded) in LDS (stride 36, b128-aligned rows)
//  - thread tile 8z x 4v: per-u 2x ds_read_b128 (x) + 1x ds_read_b128 (w) per 32 FMA
//  - segment from counts prefix-scan; uniform-segment fast path, general fallback.

constexpr int S = 8, U = 32, V = 32, C = 32, Z = 65536;
constexpr int BZ = 128;      // z rows per block
constexpr int NT = 128;      // threads per block (2 waves)
constexpr int ZS = BZ + 4;   // 132: X^T row stride (16B-aligned reads, 2-way banks only)
constexpr int WS = 36;       // W row stride (16B-aligned b128 reads, conflict-free)

typedef float f4 __attribute__((ext_vector_type(4)));

__global__ __launch_bounds__(NT) void IndexedLinear_kernel(
    const float* __restrict__ W_all,   // (C, S*U*V)
    const float* __restrict__ X,       // (Z, S*U)
    const int*   __restrict__ counts,  // (C,)
    const float* __restrict__ coeff,   // (S,)
    float*       __restrict__ out)     // (Z, S*V)
{
  const int tid = threadIdx.x;
  const int s   = blockIdx.x & 7;   // s index
  const int zb  = blockIdx.x >> 3;  // z tile
  const int z0  = zb * BZ;

  __shared__ float XT[U * ZS];
  __shared__ float Wl[U * WS];
  __shared__ int   pre[C + 1];
  __shared__ int   sseg0, suni;

  // ---- prefix sum of counts (exclusive): pre[c] = start z of segment c ----
  if (tid <= C) {
    int a = 0;
    for (int i = 0; i < tid; ++i) a += counts[i];  // C=32, L1-cached, once/block
    pre[tid] = a;
  }
  __syncthreads();

  if (tid == 0) {
    // seg(z) = max{ c : pre[c] <= z } (clips to C-1, matching jnp gather clip)
    int a = 0, b = 0;
    #pragma unroll
    for (int i = 1; i < C; ++i) {
      if (pre[i] <= z0) a = i;
      if (pre[i] <= z0 + BZ - 1) b = i;
    }
    sseg0 = a;
    suni  = (a == b);
  }
  __syncthreads();

  const int   seg0 = sseg0;
  const int   uni  = suni;
  const float cs   = coeff[s];

  // ---- stage X^T: 128 z x 32 u for this s ----
  const int ug = tid & 7;    // float4 group along u
  const int zl = tid >> 3;   // 0..15
  f4 xv[8];
  const float* xbase = X + (size_t)z0 * (S * U) + s * U + ug * 4;
  #pragma unroll
  for (int p = 0; p < 8; ++p) {
    xv[p] = *(const f4*)(xbase + (size_t)(p * 16 + zl) * (S * U));
  }

  // ---- stage W for seg0 with coeff folded in (harmless if !uni) ----
  {
    const float* wbase = W_all + (size_t)seg0 * (S * U * V) + s * (U * V);
    #pragma unroll
    for (int k = 0; k < 2; ++k) {
      const int idx = tid + k * NT;              // 0..255 float4s
      f4 wv = *(const f4*)(wbase + idx * 4);     // fully coalesced
      wv *= cs;
      const int wu = idx >> 3, wc = (idx & 7) * 4;
      *(f4*)&Wl[wu * WS + wc] = wv;
    }
  }

  // transpose-scatter x into LDS
  #pragma unroll
  for (int p = 0; p < 8; ++p) {
    const int z = p * 16 + zl;
    #pragma unroll
    for (int j = 0; j < 4; ++j) XT[(ug * 4 + j) * ZS + z] = xv[p][j];
  }
  __syncthreads();

  // ---- compute: thread tile 8z x 4v ----
  const int vg = tid & 7;    // v group (4 v's)
  const int zg = tid >> 3;   // 0..15 (8 z's each)
  float acc[8][4] = {};

  if (uni) {
    #pragma unroll
    for (int u = 0; u < U; ++u) {
      const f4 w  = *(const f4*)&Wl[u * WS + vg * 4];
      const f4 xa = *(const f4*)&XT[u * ZS + zg * 8];
      const f4 xb = *(const f4*)&XT[u * ZS + zg * 8 + 4];
      #pragma unroll
      for (int j = 0; j < 4; ++j) {
        #pragma unroll
        for (int i = 0; i < 4; ++i) {
          acc[i][j]     += xa[i] * w[j];
          acc[4 + i][j] += xb[i] * w[j];
        }
      }
    }
  } else {
    // general fallback: per-z segment lookup, W from global (coeff applied at end)
    #pragma unroll 1
    for (int zi = 0; zi < 8; ++zi) {
      const int z = z0 + zg * 8 + zi;
      int sg = 0;
      #pragma unroll 1
      for (int i = 1; i < C; ++i) if (pre[i] <= z) sg = i;
      const float* wb = W_all + (size_t)sg * (S * U * V) + s * (U * V) + vg * 4;
      #pragma unroll 1
      for (int u = 0; u < U; ++u) {
        const float xs = XT[u * ZS + zg * 8 + zi];
        #pragma unroll
        for (int j = 0; j < 4; ++j) acc[zi][j] += xs * wb[u * V + j];
      }
      #pragma unroll
      for (int j = 0; j < 4; ++j) acc[zi][j] *= cs;
    }
  }

  // ---- store: float4 per z row ----
  float* ob = out + (size_t)(z0 + zg * 8) * (S * V) + s * V + vg * 4;
  #pragma unroll
  for (int zi = 0; zi < 8; ++zi) {
    f4 o;
    o[0] = acc[zi][0]; o[1] = acc[zi][1]; o[2] = acc[zi][2]; o[3] = acc[zi][3];
    *(f4*)(ob + (size_t)zi * (S * V)) = o;
  }
}

extern "C" void kernel_launch(void* const* d_in, const int* in_sizes, int n_in,
                              void* d_out, int out_size, void* d_ws, size_t ws_size,
                              hipStream_t stream) {
  const float* input1       = (const float*)d_in[0];  // (C, S*U*V)
  const float* input2       = (const float*)d_in[1];  // (Z, S*U)
  const int*   counts       = (const int*)d_in[2];    // (C,)
  const float* coefficients = (const float*)d_in[3];  // (S,)
  float*       out          = (float*)d_out;          // (Z, S*V)

  const int grid = (Z / BZ) * S;  // 4096 blocks
  IndexedLinear_kernel<<<grid, NT, 0, stream>>>(input1, input2, counts,
                                                coefficients, out);
}